// Round 5
// baseline (225.423 us; speedup 1.0000x reference)
//
#include <hip/hip_runtime.h>
#include <hip/hip_bf16.h>
#include <math.h>

// Problem constants (B=2, C=256, H=W=64, D=4, K=9, K2=81)
#define BATCH 2
#define CCH   256
#define HH    64
#define WW    64
#define PIX   (HH*WW)          // 4096
#define K2    81
#define BP_N  (BATCH*PIX)      // 8192

// ---------------------------------------------------------------------------
// Prep kernel: NCHW->NHWC transposes (blocks 0..4095) + w1t (4096..4223) +
// w2t (4224..4367).  One launch instead of two (R15->R17 measured ~3 µs per
// launch).  Bodies verbatim from R18's k_transpose2 / k_wprep.
// ---------------------------------------------------------------------------
__global__ void k_prep(const float* __restrict__ feat,
                       const float* __restrict__ feat_ref,
                       float* __restrict__ featT,
                       float* __restrict__ refT,
                       const float* __restrict__ w1, float* __restrict__ w1t,
                       const float* __restrict__ w2, float* __restrict__ w2t) {
    __shared__ float tile[32][33];
    int blk = blockIdx.x;
    int tx  = threadIdx.x;    // 32
    int ty  = threadIdx.y;    // 8
    int tid = ty * 32 + tx;
    if (blk < 4096) {
        int z   = blk >> 10;
        int rem = blk & 1023;
        int c0  = (rem >> 7) * 32;
        int p0  = (rem & 127) * 32;
        int b   = z & 1;
        const float* in  = (z >> 1) ? feat_ref : feat;
        float*       out = (z >> 1) ? refT     : featT;
        const float* ib = in  + (size_t)b * CCH * PIX;
        float*       ob = out + (size_t)b * CCH * PIX;
        #pragma unroll
        for (int i = 0; i < 4; i++) {
            int c = c0 + ty + i * 8;
            int p = p0 + tx;
            tile[ty + i * 8][tx] = ib[(size_t)c * PIX + p];
        }
        __syncthreads();
        #pragma unroll
        for (int i = 0; i < 4; i++) {
            int p = p0 + ty + i * 8;
            int c = c0 + tx;
            ob[(size_t)p * CCH + c] = tile[tx][ty + i * 8];
        }
    } else if (blk < 4224) {
        int wb = blk - 4096;
        int c0 = (wb & 15) * 32;
        int o0 = (wb >> 4) * 32;
        #pragma unroll
        for (int i = 0; i < 4; i++)
            tile[ty + i * 8][tx] = w1[(size_t)(o0 + ty + i * 8) * 512 + c0 + tx];
        __syncthreads();
        #pragma unroll
        for (int i = 0; i < 4; i++)
            w1t[(size_t)(c0 + ty + i * 8) * 256 + o0 + tx] = tile[tx][ty + i * 8];
    } else {
        int i = (blk - 4224) * 256 + tid;
        if (i < 16 * 256 * 9) {
            int o  = i / 2304;
            int r  = i % 2304;        // c*9 + kk
            int c  = r / 9;
            int kk = r % 9;
            int cg = c >> 2, ci = c & 3;
            w2t[(((kk * 64 + cg) * 16 + o) << 2) + ci] = w2[i];
        }
    }
}

// ---------------------------------------------------------------------------
// Correlation + sum-normalize + assemble, PPB=4 (pixel quad per block).
// BIT-EXACT recipe preserved per (pixel,k):
//   phase 1: per-k t=0..7 ascending fmaf chain, butterfly xor 8,16,4,2,1
//   phase 2: sequential ascending-k fp32 add chain over ALL 81 (zeros incl.)
//   phase 3: sequential ascending-k fmaf chain; union entries not serving a
//            pixel carry coefficient exactly +0.0f (fmaf(+0,v,acc) identity).
//
// R19: four adjacent pixels (w..w+3) share a 9x12 union window (108 px vs
// 180 for two PPB2 pairs) -> phase-1/phase-3 ref loads -40%, compaction/
// barriers/phase-2 amortized 4x, blocks halve to 2048.  Each union slice
// feeds up to 8 chains per slice-pair (full ILP, invalid chains computed but
// never written — exact no-ops as in R17).  Phase 3 adds R18-style double-
// register-set pipelining (batch k+1 loads fly under batch k's FMAs).
// Union u=(uy,ux), uy 0..8, ux 0..11; pixel i's k=(uy,ux-i), valid iff
// 0<=ux-i<=8.  All 4 pixels reference the SAME ref pixel for their k's.
// XCD swizzle retained (256-quad bands = 16-row bands per XCD).
// ---------------------------------------------------------------------------
__global__ void k_corr_assemble(const float* __restrict__ featT,
                                const float* __restrict__ refT,
                                float* __restrict__ alignedT) {
    int blk = blockIdx.x;                        // 0..2047
    int qd  = ((blk & 7) << 8) | (blk >> 3);     // XCD-contiguous quad bands
    int bp  = qd << 2;                           // first pixel of quad
    int b  = bp >> 12;
    int p  = bp & 4095;
    int h  = p >> 6, w = p & 63;                 // w % 4 == 0
    int tid = threadIdx.x;                       // 0..255

    __shared__ float s_aff[4][K2];
    __shared__ __align__(8) int2 s_u[112];       // compacted (poff, meta)
    __shared__ int   s_hi_a[48];
    __shared__ int   s_hi_b[48];
    __shared__ int   s_cnt0, s_cnt1;
    __shared__ float s_den[4];
    __shared__ __align__(16) float s_c[4][112];  // per-pixel coeffs
    __shared__ __align__(16) int   s_po[112];    // byte offsets

    int hw = tid >> 5;        // 0..7
    int j  = tid & 31;        // 0..31

    // feat fragments for all 4 pixels in registers
    const float* fb = featT + ((size_t)bp << 8) + j;
    float f0[8], f1[8], f2[8], f3[8];
    #pragma unroll
    for (int t = 0; t < 8; t++) {
        f0[t] = fb[32 * t];
        f1[t] = fb[256 + 32 * t];
        f2[t] = fb[512 + 32 * t];
        f3[t] = fb[768 + 32 * t];
    }

    if (tid < K2) {
        s_aff[0][tid] = 0.f; s_aff[1][tid] = 0.f;
        s_aff[2][tid] = 0.f; s_aff[3][tid] = 0.f;
    }

    // --- compacted union list (108 candidates), order-preserving ---
    if (tid < 128) {
        int u  = tid;
        int uy = u / 12, ux = u - uy * 12;
        int y  = h + uy - 4, x = w + ux - 4;
        bool valid = (u < 108) && ((unsigned)y < 64u) && ((unsigned)x < 64u);
        int poff = ((y << 6) | x) << 10;          // pix*256*4 bytes
        int meta = (ux << 8) | (uy * 9 + ux);     // base k = uy*9+ux
        unsigned long long m = __ballot(valid);
        int lane   = tid & 63;
        int prefix = __popcll(m & ((1ULL << lane) - 1ULL));
        if (tid < 64) {
            if (valid) s_u[prefix] = make_int2(poff, meta);
            if (tid == 0) s_cnt0 = (int)__popcll(m);
        } else {
            if (valid) { s_hi_a[prefix] = poff; s_hi_b[prefix] = meta; }
            if (tid == 64) s_cnt1 = (int)__popcll(m);
        }
    }
    __syncthreads();
    int n0 = s_cnt0, n1 = s_cnt1;
    int nu = n0 + n1;                  // uniform across block (40..108)
    if (tid < n1) s_u[n0 + tid] = make_int2(s_hi_a[tid], s_hi_b[tid]);
    __syncthreads();

    const float* rb  = refT + ((size_t)b << 20);   // b*4096*256
    const char*  rbj = (const char*)rb + 4 * j;

    // Phase 1 (pipelined): 2 union slices per group-iter, 8 chains in flight.
    int ii = 2 * hw;
    bool act = ii < nu;
    int2 U0 = make_int2(0, 0), U1 = make_int2(0, 0);
    bool has1 = false;
    float r0[8], r1[8];
    if (act) {
        U0 = s_u[ii];
        has1 = (ii + 1) < nu;
        U1 = has1 ? s_u[ii + 1] : U0;
        const char* rp0 = rbj + U0.x;
        const char* rp1 = rbj + U1.x;
        #pragma unroll
        for (int t = 0; t < 8; t++) {
            r0[t] = *(const float*)(rp0 + 128 * t);
            r1[t] = *(const float*)(rp1 + 128 * t);
        }
    }
    while (act) {
        float p00 = 0.f, p01 = 0.f, p02 = 0.f, p03 = 0.f;
        float p10 = 0.f, p11 = 0.f, p12 = 0.f, p13 = 0.f;
        #pragma unroll
        for (int t = 0; t < 8; t++) {
            p00 = fmaf(f0[t], r0[t], p00);
            p01 = fmaf(f1[t], r0[t], p01);
            p02 = fmaf(f2[t], r0[t], p02);
            p03 = fmaf(f3[t], r0[t], p03);
            p10 = fmaf(f0[t], r1[t], p10);
            p11 = fmaf(f1[t], r1[t], p11);
            p12 = fmaf(f2[t], r1[t], p12);
            p13 = fmaf(f3[t], r1[t], p13);
        }
        int  m0c = U0.y, m1c = U1.y;
        bool h1c = has1;

        // prefetch next iteration (loads fly during the shuffle chains)
        ii += 16;
        bool nact = ii < nu;
        if (nact) {
            U0 = s_u[ii];
            has1 = (ii + 1) < nu;
            U1 = has1 ? s_u[ii + 1] : U0;
            const char* rp0 = rbj + U0.x;
            const char* rp1 = rbj + U1.x;
            #pragma unroll
            for (int t = 0; t < 8; t++) {
                r0[t] = *(const float*)(rp0 + 128 * t);
                r1[t] = *(const float*)(rp1 + 128 * t);
            }
        }

        // butterfly xor 8,16,4,2,1 — order unchanged per chain
#define BFLY(MASK)                                        \
        p00 = __fadd_rn(p00, __shfl_xor(p00, MASK));      \
        p01 = __fadd_rn(p01, __shfl_xor(p01, MASK));      \
        p02 = __fadd_rn(p02, __shfl_xor(p02, MASK));      \
        p03 = __fadd_rn(p03, __shfl_xor(p03, MASK));      \
        p10 = __fadd_rn(p10, __shfl_xor(p10, MASK));      \
        p11 = __fadd_rn(p11, __shfl_xor(p11, MASK));      \
        p12 = __fadd_rn(p12, __shfl_xor(p12, MASK));      \
        p13 = __fadd_rn(p13, __shfl_xor(p13, MASK));
        BFLY(8)
        BFLY(16)
        BFLY(4)
        BFLY(2)
        BFLY(1)
#undef BFLY

        if (j == 0) {
            int base0 = m0c & 255, ux0 = m0c >> 8;
            if (ux0 <= 8)              s_aff[0][base0]     = p00;
            if (ux0 >= 1 && ux0 <= 9)  s_aff[1][base0 - 1] = p01;
            if (ux0 >= 2 && ux0 <= 10) s_aff[2][base0 - 2] = p02;
            if (ux0 >= 3)              s_aff[3][base0 - 3] = p03;
            if (h1c) {
                int base1 = m1c & 255, ux1 = m1c >> 8;
                if (ux1 <= 8)              s_aff[0][base1]     = p10;
                if (ux1 >= 1 && ux1 <= 9)  s_aff[1][base1 - 1] = p11;
                if (ux1 >= 2 && ux1 <= 10) s_aff[2][base1 - 2] = p12;
                if (ux1 >= 3)              s_aff[3][base1 - 3] = p13;
            }
        }
        act = nact;
    }
    __syncthreads();

    // Phase 2: sequential ascending-k fp32 add chain over ALL 81, per pixel.
    if (tid < 4) {
        const float* sa = s_aff[tid];
        float s = 0.f;
        for (int k = 0; k < K2; k++) s = __fadd_rn(s, sa[k]);
        s_den[tid] = __fadd_rn(s, 1e-7f);
    }
    __syncthreads();

    // Per-union coefficients (entries not serving a pixel get exact +0.0f).
    if (tid < nu) {
        int2 uu = s_u[tid];
        int base = uu.y & 255, ux = uu.y >> 8;
        s_po[tid] = uu.x;
        s_c[0][tid] = (ux <= 8)              ? __fdiv_rn(s_aff[0][base],     s_den[0]) : 0.f;
        s_c[1][tid] = (ux >= 1 && ux <= 9)   ? __fdiv_rn(s_aff[1][base - 1], s_den[1]) : 0.f;
        s_c[2][tid] = (ux >= 2 && ux <= 10)  ? __fdiv_rn(s_aff[2][base - 2], s_den[2]) : 0.f;
        s_c[3][tid] = (ux >= 3)              ? __fdiv_rn(s_aff[3][base - 3], s_den[3]) : 0.f;
    }
    __syncthreads();

    // Phase 3: ascending union list = ascending k per pixel; each loaded
    // value feeds 4 pixels' FMA chains.  Double-register-set pipeline.
    const char* rbc = (const char*)rb + ((size_t)tid << 2);
    float a0 = 0.f, a1 = 0.f, a2 = 0.f, a3 = 0.f;
    float vA[8], vB[8];

#define LOADV(V, BASE) do {                                                   \
        int4 pA_ = *(const int4*)&s_po[BASE];                                 \
        int4 pB_ = *(const int4*)&s_po[(BASE) + 4];                           \
        V[0] = *(const float*)(rbc + pA_.x);                                  \
        V[1] = *(const float*)(rbc + pA_.y);                                  \
        V[2] = *(const float*)(rbc + pA_.z);                                  \
        V[3] = *(const float*)(rbc + pA_.w);                                  \
        V[4] = *(const float*)(rbc + pB_.x);                                  \
        V[5] = *(const float*)(rbc + pB_.y);                                  \
        V[6] = *(const float*)(rbc + pB_.z);                                  \
        V[7] = *(const float*)(rbc + pB_.w);                                  \
    } while (0)

#define FMA8(V, BASE) do {                                                    \
        float4 c0a = *(const float4*)&s_c[0][BASE];                           \
        float4 c0b = *(const float4*)&s_c[0][(BASE) + 4];                     \
        float4 c1a = *(const float4*)&s_c[1][BASE];                           \
        float4 c1b = *(const float4*)&s_c[1][(BASE) + 4];                     \
        float4 c2a = *(const float4*)&s_c[2][BASE];                           \
        float4 c2b = *(const float4*)&s_c[2][(BASE) + 4];                     \
        float4 c3a = *(const float4*)&s_c[3][BASE];                           \
        float4 c3b = *(const float4*)&s_c[3][(BASE) + 4];                     \
        a0 = fmaf(c0a.x, V[0], a0); a1 = fmaf(c1a.x, V[0], a1);               \
        a2 = fmaf(c2a.x, V[0], a2); a3 = fmaf(c3a.x, V[0], a3);               \
        a0 = fmaf(c0a.y, V[1], a0); a1 = fmaf(c1a.y, V[1], a1);               \
        a2 = fmaf(c2a.y, V[1], a2); a3 = fmaf(c3a.y, V[1], a3);               \
        a0 = fmaf(c0a.z, V[2], a0); a1 = fmaf(c1a.z, V[2], a1);               \
        a2 = fmaf(c2a.z, V[2], a2); a3 = fmaf(c3a.z, V[2], a3);               \
        a0 = fmaf(c0a.w, V[3], a0); a1 = fmaf(c1a.w, V[3], a1);               \
        a2 = fmaf(c2a.w, V[3], a2); a3 = fmaf(c3a.w, V[3], a3);               \
        a0 = fmaf(c0b.x, V[4], a0); a1 = fmaf(c1b.x, V[4], a1);               \
        a2 = fmaf(c2b.x, V[4], a2); a3 = fmaf(c3b.x, V[4], a3);               \
        a0 = fmaf(c0b.y, V[5], a0); a1 = fmaf(c1b.y, V[5], a1);               \
        a2 = fmaf(c2b.y, V[5], a2); a3 = fmaf(c3b.y, V[5], a3);               \
        a0 = fmaf(c0b.z, V[6], a0); a1 = fmaf(c1b.z, V[6], a1);               \
        a2 = fmaf(c2b.z, V[6], a2); a3 = fmaf(c3b.z, V[6], a3);               \
        a0 = fmaf(c0b.w, V[7], a0); a1 = fmaf(c1b.w, V[7], a1);               \
        a2 = fmaf(c2b.w, V[7], a2); a3 = fmaf(c3b.w, V[7], a3);               \
    } while (0)

    int i = 0;
    if (nu >= 8) {
        LOADV(vA, 0);
        for (i = 0; i + 8 <= nu; i += 8) {
            bool more = (i + 16 <= nu);
            if (((i >> 3) & 1) == 0) {
                if (more) LOADV(vB, i + 8);
                FMA8(vA, i);
            } else {
                if (more) LOADV(vA, i + 8);
                FMA8(vB, i);
            }
        }
    }
    for (; i < nu; i++) {
        float v = *(const float*)(rbc + s_po[i]);
        a0 = fmaf(s_c[0][i], v, a0);
        a1 = fmaf(s_c[1][i], v, a1);
        a2 = fmaf(s_c[2][i], v, a2);
        a3 = fmaf(s_c[3][i], v, a3);
    }
#undef LOADV
#undef FMA8

    alignedT[((size_t)bp << 8) + tid]       = a0;
    alignedT[((size_t)(bp + 1) << 8) + tid] = a1;
    alignedT[((size_t)(bp + 2) << 8) + tid] = a2;
    alignedT[((size_t)(bp + 3) << 8) + tid] = a3;
}

// ---------------------------------------------------------------------------
// Conv1: 1x1, 512 -> 256, FP32 GEMM (numerics-free; kc asc, k asc chain).
// R18 double-buffered version, verbatim.
// ---------------------------------------------------------------------------
__global__ void k_conv1(const float* __restrict__ featT,
                        const float* __restrict__ alignedT,
                        const float* __restrict__ w1t,
                        const float* __restrict__ b1,
                        float* __restrict__ h1) {
    __shared__ float s_a[2][32][68];     // [buf][k][px]
    __shared__ float s_b[2][32][68];     // [buf][k][o]
    int m0  = blockIdx.x * 64;        // pixel base
    int n0  = blockIdx.y * 64;        // out-channel base
    int tid = threadIdx.x;
    int tx  = tid & 15;               // o quad
    int ty  = tid >> 4;               // px quad
    int cq  = tid & 7;                // a-stage: c quad
    int pxa = tid >> 3;               // a-stage: px 0..31
    int oq  = tid & 15;               // b-stage: o quad
    int cc  = tid >> 4;               // b-stage: c 0..15

    float acc[4][4] = {{0.f}};
    float4 ra0, ra1, rb0, rb1;

#define C1_LOAD(kc_) do {                                                     \
        int c0_ = (kc_) * 32;                                                 \
        const float* asrc_ = (c0_ < 256) ? featT : alignedT;                  \
        int coff_ = (c0_ < 256) ? c0_ : c0_ - 256;                            \
        ra0 = *(const float4*)(asrc_ + ((size_t)(m0 + pxa) << 8) + coff_ + (cq << 2));      \
        ra1 = *(const float4*)(asrc_ + ((size_t)(m0 + 32 + pxa) << 8) + coff_ + (cq << 2)); \
        rb0 = *(const float4*)(w1t + (size_t)(c0_ + cc) * 256 + n0 + (oq << 2));            \
        rb1 = *(const float4*)(w1t + (size_t)(c0_ + 16 + cc) * 256 + n0 + (oq << 2));       \
    } while (0)

#define C1_WRITE(bf_) do {                                                    \
        s_a[bf_][cq * 4 + 0][pxa] = ra0.x;                                    \
        s_a[bf_][cq * 4 + 1][pxa] = ra0.y;                                    \
        s_a[bf_][cq * 4 + 2][pxa] = ra0.z;                                    \
        s_a[bf_][cq * 4 + 3][pxa] = ra0.w;                                    \
        s_a[bf_][cq * 4 + 0][32 + pxa] = ra1.x;                               \
        s_a[bf_][cq * 4 + 1][32 + pxa] = ra1.y;                               \
        s_a[bf_][cq * 4 + 2][32 + pxa] = ra1.z;                               \
        s_a[bf_][cq * 4 + 3][32 + pxa] = ra1.w;                               \
        *(float4*)&s_b[bf_][cc][oq << 2] = rb0;                               \
        *(float4*)&s_b[bf_][16 + cc][oq << 2] = rb1;                          \
    } while (0)

    C1_LOAD(0);
    C1_WRITE(0);
    __syncthreads();

    for (int kc = 0; kc < 16; kc++) {
        int cur = kc & 1;
        if (kc < 15) C1_LOAD(kc + 1);     // loads fly during compute

        #pragma unroll 8
        for (int k = 0; k < 32; k++) {
            float4 av = *(const float4*)&s_a[cur][k][ty << 2];
            float4 bv = *(const float4*)&s_b[cur][k][tx << 2];
            acc[0][0] = fmaf(av.x, bv.x, acc[0][0]);
            acc[0][1] = fmaf(av.x, bv.y, acc[0][1]);
            acc[0][2] = fmaf(av.x, bv.z, acc[0][2]);
            acc[0][3] = fmaf(av.x, bv.w, acc[0][3]);
            acc[1][0] = fmaf(av.y, bv.x, acc[1][0]);
            acc[1][1] = fmaf(av.y, bv.y, acc[1][1]);
            acc[1][2] = fmaf(av.y, bv.z, acc[1][2]);
            acc[1][3] = fmaf(av.y, bv.w, acc[1][3]);
            acc[2][0] = fmaf(av.z, bv.x, acc[2][0]);
            acc[2][1] = fmaf(av.z, bv.y, acc[2][1]);
            acc[2][2] = fmaf(av.z, bv.z, acc[2][2]);
            acc[2][3] = fmaf(av.z, bv.w, acc[2][3]);
            acc[3][0] = fmaf(av.w, bv.x, acc[3][0]);
            acc[3][1] = fmaf(av.w, bv.y, acc[3][1]);
            acc[3][2] = fmaf(av.w, bv.z, acc[3][2]);
            acc[3][3] = fmaf(av.w, bv.w, acc[3][3]);
        }

        if (kc < 15) C1_WRITE(cur ^ 1);
        __syncthreads();
    }

    float4 bias = *(const float4*)(b1 + n0 + tx * 4);
    #pragma unroll
    for (int i = 0; i < 4; i++) {
        int px = m0 + ty * 4 + i;
        float4 v;
        v.x = acc[i][0] + bias.x;
        v.y = acc[i][1] + bias.y;
        v.z = acc[i][2] + bias.z;
        v.w = acc[i][3] + bias.w;
        *(float4*)(h1 + ((size_t)px << 8) + n0 + tx * 4) = v;
    }
}

// ---------------------------------------------------------------------------
// Conv2: 3x3 pad1, 256 -> 16, FP32, numerics-free.  Verbatim from R12.
// ---------------------------------------------------------------------------
__global__ void k_conv2(const float* __restrict__ h1,
                        const float* __restrict__ w2t,
                        const float* __restrict__ b2,
                        float* __restrict__ h2) {
    __shared__ float s_in[3][18][68];
    int blk = blockIdx.x;          // 0..511
    int b   = blk >> 8;            // 256 blocks per batch
    int r   = blk & 255;
    int y   = r >> 2;
    int w0  = (r & 3) * 16;
    int tid = threadIdx.x;
    int o   = tid & 15;
    int ps  = (tid >> 4) & 7;      // slot 0..7 -> pixels ps, ps+8

    const float* hb = h1 + ((size_t)b << 20);

    float4 a0 = {0.f, 0.f, 0.f, 0.f};
    float4 a1 = {0.f, 0.f, 0.f, 0.f};

    for (int chunk = 0; chunk < 4; chunk++) {
        int c0 = chunk << 6;
        for (int i = tid; i < 3 * 18 * 16; i += 256) {
            int c4 = i & 15;
            int pi = (i >> 4) % 18;
            int ri = (i >> 4) / 18;
            int yy = y + ri - 1;
            int xx = w0 + pi - 1;
            float4 v = {0.f, 0.f, 0.f, 0.f};
            if ((unsigned)yy < 64u && (unsigned)xx < 64u)
                v = *(const float4*)(hb + ((size_t)((yy << 6) | xx) << 8) + c0 + (c4 << 2));
            *(float4*)&s_in[ri][pi][c4 << 2] = v;
        }
        __syncthreads();

        #pragma unroll
        for (int kk = 0; kk < 9; kk++) {
            int ky = kk / 3, kx = kk - ky * 3;
            const float* wp = w2t + (((size_t)(kk * 64 + (c0 >> 2)) * 16 + o) << 2);
            #pragma unroll 8
            for (int c4 = 0; c4 < 16; c4++) {
                float4 wv = *(const float4*)(wp + (c4 << 6));
                float4 i0 = *(const float4*)&s_in[ky][ps + kx][c4 << 2];
                float4 i1 = *(const float4*)&s_in[ky][ps + 8 + kx][c4 << 2];
                a0.x = fmaf(wv.x, i0.x, a0.x);
                a0.y = fmaf(wv.y, i0.y, a0.y);
                a0.z = fmaf(wv.z, i0.z, a0.z);
                a0.w = fmaf(wv.w, i0.w, a0.w);
                a1.x = fmaf(wv.x, i1.x, a1.x);
                a1.y = fmaf(wv.y, i1.y, a1.y);
                a1.z = fmaf(wv.z, i1.z, a1.z);
                a1.w = fmaf(wv.w, i1.w, a1.w);
            }
        }
        __syncthreads();
    }

    size_t bp0 = ((size_t)b << 12) + (y << 6) + w0;
    h2[(bp0 + ps) * 16 + o]     = ((a0.x + a0.y) + (a0.z + a0.w)) + b2[o];
    h2[(bp0 + ps + 8) * 16 + o] = ((a1.x + a1.y) + (a1.z + a1.w)) + b2[o];
}

// ---------------------------------------------------------------------------
// Conv3: 3x3 pad1, 16 -> 3, FP32, numerics-free.  Thread per pixel.
// ---------------------------------------------------------------------------
__global__ void k_conv3(const float* __restrict__ h2,
                        const float* __restrict__ w3,
                        const float* __restrict__ b3,
                        float* __restrict__ h3) {
    int bp = blockIdx.x * 256 + threadIdx.x;
    if (bp >= BP_N) return;
    int b = bp >> 12;
    int p = bp & 4095;
    int h = p >> 6, w = p & 63;
    const float* hb = h2 + ((size_t)b << 16);   // b*4096*16

    float a0 = 0.f, a1 = 0.f, a2 = 0.f;
    #pragma unroll
    for (int kk = 0; kk < 9; kk++) {
        int ky = kk / 3, kx = kk - ky * 3;
        int y = h + ky - 1, x = w + kx - 1;
        if ((unsigned)y >= 64u || (unsigned)x >= 64u) continue;
        const float* ip = hb + (size_t)((y << 6) | x) * 16;
        #pragma unroll
        for (int c = 0; c < 16; c++) {
            float v = ip[c];
            int wi = c * 9 + kk;
            a0 = fmaf(w3[wi],       v, a0);
            a1 = fmaf(w3[144 + wi], v, a1);
            a2 = fmaf(w3[288 + wi], v, a2);
        }
    }
    h3[(size_t)bp * 3 + 0] = a0 + b3[0];
    h3[(size_t)bp * 3 + 1] = a1 + b3[1];
    h3[(size_t)bp * 3 + 2] = a2 + b3[2];
}

// ---------------------------------------------------------------------------
// Conv4 (3x3, 3 -> 2) + softmax -> (score0, score1), FP32, numerics-free.
// ---------------------------------------------------------------------------
__global__ void k_score(const float* __restrict__ h3,
                        const float* __restrict__ w4,
                        const float* __restrict__ b4,
                        float2* __restrict__ score) {
    int bp = blockIdx.x * 256 + threadIdx.x;
    if (bp >= BP_N) return;
    int b = bp >> 12;
    int p = bp & 4095;
    int h = p >> 6, w = p & 63;
    const float* hb = h3 + (size_t)b * PIX * 3;

    float l0 = 0.f, l1 = 0.f;
    #pragma unroll
    for (int kk = 0; kk < 9; kk++) {
        int ky = kk / 3, kx = kk - ky * 3;
        int y = h + ky - 1, x = w + kx - 1;
        if ((unsigned)y >= 64u || (unsigned)x >= 64u) continue;
        const float* ip = hb + (size_t)((y << 6) | x) * 3;
        #pragma unroll
        for (int c = 0; c < 3; c++) {
            float v = ip[c];
            int wi = c * 9 + kk;
            l0 = fmaf(w4[wi],      v, l0);
            l1 = fmaf(w4[27 + wi], v, l1);
        }
    }
    l0 += b4[0];
    l1 += b4[1];

    float m  = fmaxf(l0, l1);
    float e0 = expf(l0 - m);
    float e1 = expf(l1 - m);
    float s  = e0 + e1;
    score[bp] = make_float2(e0 / s, e1 / s);
}

// ---------------------------------------------------------------------------
// Blend + on-the-fly NHWC->NCHW transpose of aligned.  Verbatim from R11.
// ---------------------------------------------------------------------------
__global__ void k_blend(const float* __restrict__ feat,
                        const float* __restrict__ alignedT,
                        const float2* __restrict__ score,
                        float* __restrict__ out) {
    __shared__ float tile[32][33];
    int b  = blockIdx.z;
    int p0 = blockIdx.x * 32;
    int c0 = blockIdx.y * 32;
    int tx = threadIdx.x;     // 32
    int ty = threadIdx.y;     // 8

    const float* at = alignedT + ((size_t)b << 20);
    #pragma unroll
    for (int i = 0; i < 4; i++) {
        int p = p0 + ty + i * 8;
        tile[ty + i * 8][tx] = at[((size_t)p << 8) + c0 + tx];
    }
    __syncthreads();

    int p = p0 + tx;
    float2 s = score[(b << 12) + p];
    #pragma unroll
    for (int i = 0; i < 4; i++) {
        int c = c0 + ty + i * 8;
        size_t idx = (((size_t)(b * 256 + c)) << 12) + p;
        out[idx] = __fadd_rn(__fmul_rn(s.x, feat[idx]),
                             __fmul_rn(s.y, tile[tx][ty + i * 8]));
    }
}

// ---------------------------------------------------------------------------
extern "C" void kernel_launch(void* const* d_in, const int* in_sizes, int n_in,
                              void* d_out, int out_size, void* d_ws, size_t ws_size,
                              hipStream_t stream) {
    const float* feat     = (const float*)d_in[0];
    const float* feat_ref = (const float*)d_in[1];
    const float* w1 = (const float*)d_in[2];
    const float* b1 = (const float*)d_in[3];
    const float* w2 = (const float*)d_in[4];
    const float* b2 = (const float*)d_in[5];
    const float* w3 = (const float*)d_in[6];
    const float* b3 = (const float*)d_in[7];
    const float* w4 = (const float*)d_in[8];
    const float* b4 = (const float*)d_in[9];
    float* out = (float*)d_out;

    const size_t NCP = (size_t)BATCH * CCH * PIX;   // 2,097,152
    char* wsb = (char*)d_ws;
    float*  featT    = (float*)wsb;   wsb += NCP * 4;               // 8 MB
    float*  refT     = (float*)wsb;   wsb += NCP * 4;               // 8 MB
    float*  alignedT = (float*)wsb;   wsb += NCP * 4;               // 8 MB
    float*  h1       = (float*)wsb;   wsb += NCP * 4;               // 8 MB
    float*  h2       = (float*)wsb;   wsb += (size_t)BP_N * 16 * 4;
    float*  h3       = (float*)wsb;   wsb += (size_t)BP_N * 3 * 4;
    float2* sc       = (float2*)wsb;  wsb += (size_t)BP_N * 8;
    float*  w2t      = (float*)wsb;   wsb += (size_t)16 * 256 * 9 * 4;
    float*  w1t      = (float*)wsb;   wsb += (size_t)512 * 256 * 4;

    dim3 tb(32, 8, 1);
    k_prep<<<4368, tb, 0, stream>>>(feat, feat_ref, featT, refT, w1, w1t, w2, w2t);

    k_corr_assemble<<<BP_N / 4, 256, 0, stream>>>(featT, refT, alignedT);
    k_conv1<<<dim3(BP_N / 64, 256 / 64, 1), 256, 0, stream>>>(featT, alignedT, w1t, b1, h1);
    k_conv2<<<BP_N / 16, 256, 0, stream>>>(h1, w2t, b2, h2);
    k_conv3<<<BP_N / 256, 256, 0, stream>>>(h2, w3, b3, h3);
    k_score<<<BP_N / 256, 256, 0, stream>>>(h3, w4, b4, sc);
    k_blend<<<dim3(PIX / 32, CCH / 32, BATCH), tb, 0, stream>>>(feat, alignedT, sc, out);
}